// Round 6
// baseline (231.552 us; speedup 1.0000x reference)
//
#include <hip/hip_runtime.h>

static constexpr int B_   = 8;
static constexpr int C_   = 256;
static constexpr int CQK_ = 32;
static constexpr int N_   = 4096;   // 64*64

typedef __attribute__((ext_vector_type(4))) float f32x4;
typedef __attribute__((ext_vector_type(8))) short short8;
typedef __attribute__((ext_vector_type(2))) unsigned int u32x2;
typedef unsigned short ushort_t;

// round-to-nearest-even fp32 -> bf16
__device__ inline unsigned short f2bf(float f) {
    unsigned u = __float_as_uint(f);
    return (unsigned short)((u + 0x7FFFu + ((u >> 16) & 1u)) >> 16);
}
__device__ inline unsigned packbf(float lo, float hi) {
    return (unsigned)f2bf(lo) | ((unsigned)f2bf(hi) << 16);
}
// packed f32->bf16 pair (RNE), single VOP3
__device__ inline unsigned cvtpk(float lo, float hi) {
    unsigned r;
    asm("v_cvt_pk_bf16_f32 %0, %1, %2" : "=v"(r) : "v"(lo), "v"(hi));
    return r;
}

// row-dependent XOR swizzle (16B granules) for the proj x-tile; involution
__device__ inline int swzbits(int m) {
    return ((m & 3) << 5) | (((m >> 3) & 1) << 4);
}

template <int OFF>
__device__ inline u32x2 tr8(unsigned a) {
    u32x2 d;
    asm volatile("ds_read_b64_tr_b16 %0, %1 offset:%2"
                 : "=v"(d) : "v"(a), "i"(OFF));
    return d;
}

__device__ inline short8 mk8(u32x2 lo, u32x2 hi) {
    union { unsigned u[4]; short8 s; } v;
    v.u[0] = lo.x; v.u[1] = lo.y; v.u[2] = hi.x; v.u[3] = hi.y;
    return v.s;
}

// ---------------------------------------------------------------------------
// prep: concat + convert weights to bf16 (Q rows pre-scaled by log2(e) so the
// attention exp becomes a bare v_exp_f32), biases to f32 array
// ---------------------------------------------------------------------------
__global__ __launch_bounds__(256) void prep_kernel(
    const float* __restrict__ Wq, const float* __restrict__ bq,
    const float* __restrict__ Wk, const float* __restrict__ bk,
    const float* __restrict__ Wv, const float* __restrict__ bv,
    ushort_t* __restrict__ Wall, float* __restrict__ ball)
{
    const int r = blockIdx.x;
    const int t = threadIdx.x;
    const float LOG2E = 1.4426950408889634f;
    const float* src;
    float bsrc, sc;
    if (r < 32)      { src = Wq + (size_t)r * C_;        bsrc = bq[r];      sc = LOG2E; }
    else if (r < 64) { src = Wk + (size_t)(r - 32) * C_; bsrc = bk[r - 32]; sc = 1.0f; }
    else             { src = Wv + (size_t)(r - 64) * C_; bsrc = bv[r - 64]; sc = 1.0f; }
    Wall[(size_t)r * C_ + t] = f2bf(src[t] * sc);
    if (t == 0) ball[r] = bsrc * sc;
}

// ---------------------------------------------------------------------------
// Projection via MFMA. Wave w owns oc-tiles tt = 4*tm + w (tm=0..4).
//  tm==0 (Q/K): C[oc][n] = mfma(W-frag, x-frag)  -> Qb/Kb row-major [n][ck]
//  tm>=1 (V):   C[n][oc] = mfma(x-frag, W-frag)  -> Vt chunked+swizzled:
//    byte addr = ((b*64 + m/64)*256 + c)*128 + ((2*(m&63)) ^ ((c&7)<<4))
// grid = 512 blocks (b = blk&7, XCD-affine), 256 threads (4 waves)
// ---------------------------------------------------------------------------
__global__ __launch_bounds__(256) void proj_kernel(
    const float* __restrict__ x,
    const ushort_t* __restrict__ Wall, const float* __restrict__ ball,
    ushort_t* __restrict__ Qb, ushort_t* __restrict__ Kb, ushort_t* __restrict__ Vt)
{
    __shared__ __align__(16) unsigned char xs[C_ * 128];   // 32 KB: [c][64n] bf16
    typedef __attribute__((address_space(3))) unsigned char lds_byte;
    const unsigned sbase = (unsigned)(size_t)(lds_byte*)xs;

    const int b  = blockIdx.x & 7;
    const int n0 = (blockIdx.x >> 3) << 6;
    const int t  = threadIdx.x;

    // ---- stage x[b, c, n0..n0+63] -> xs[c][n] bf16 (swizzled rows) ----
    {
        const int cst = t >> 4;
        const int n4  = (t & 15) << 2;
        const float* xb = x + (size_t)b * C_ * N_ + n0;
        #pragma unroll
        for (int i = 0; i < 16; ++i) {
            const int c = 16 * i + cst;
            float4 v = *(const float4*)(xb + (size_t)c * N_ + n4);
            u32x2 pk;
            pk.x = packbf(v.x, v.y);
            pk.y = packbf(v.z, v.w);
            *(u32x2*)(xs + c * 128 + ((n4 * 2) ^ swzbits(c))) = pk;
        }
    }
    __syncthreads();

    const int l  = t & 63, w = t >> 6;
    const int li = l & 15, g = l >> 4;
    const int rr = li >> 2, ss = l & 3;
    const int swz_tr = (rr << 5) | ((g & 1) << 4);

    f32x4 acc[5][4];
    #pragma unroll
    for (int i = 0; i < 5; ++i)
        #pragma unroll
        for (int j = 0; j < 4; ++j) acc[i][j] = (f32x4){0.f, 0.f, 0.f, 0.f};

    #pragma unroll 2
    for (int kg = 0; kg < 8; ++kg) {
        u32x2 pb[4][2];
        #pragma unroll
        for (int jn = 0; jn < 4; ++jn) {
            unsigned a = sbase + (32 * kg + 8 * g + rr) * 128
                       + ((32 * jn + 8 * ss) ^ swz_tr);
            pb[jn][0] = tr8<0>(a);
            pb[jn][1] = tr8<512>(a);
        }
        short8 af[5];
        #pragma unroll
        for (int tm = 0; tm < 5; ++tm)
            af[tm] = *(const short8*)(Wall + (size_t)(16 * (4 * tm + w) + li) * C_
                                      + 32 * kg + 8 * g);
        asm volatile("s_waitcnt lgkmcnt(0)" ::: "memory");
        __builtin_amdgcn_sched_barrier(0);
        #pragma unroll
        for (int jn = 0; jn < 4; ++jn) {
            short8 Bf = mk8(pb[jn][0], pb[jn][1]);
            acc[0][jn] = __builtin_amdgcn_mfma_f32_16x16x32_bf16(
                             af[0], Bf, acc[0][jn], 0, 0, 0);
            #pragma unroll
            for (int tm = 1; tm < 5; ++tm)
                acc[tm][jn] = __builtin_amdgcn_mfma_f32_16x16x32_bf16(
                                  Bf, af[tm], acc[tm][jn], 0, 0, 0);
        }
    }

    // ---- epilogue ----
    {
        const int oc0 = 16 * w + 4 * g;
        float4 bias = *(const float4*)(ball + oc0);
        ushort_t* dst = (w < 2) ? Qb : Kb;
        const int col = (w < 2) ? oc0 : (oc0 - 32);
        #pragma unroll
        for (int jn = 0; jn < 4; ++jn) {
            const int n = n0 + 16 * jn + li;
            f32x4 a = acc[0][jn];
            u32x2 pk;
            pk.x = packbf(a[0] + bias.x, a[1] + bias.y);
            pk.y = packbf(a[2] + bias.z, a[3] + bias.w);
            *(u32x2*)(dst + (size_t)(b * N_ + n) * CQK_ + col) = pk;
        }
    }
    {
        const int sx = (li & 7) << 4;
        #pragma unroll
        for (int tm = 1; tm < 5; ++tm) {
            const int c  = 16 * (4 * tm + w) + li - 64;
            const float bc = ball[64 + c];
            char* vrow = (char*)Vt
                       + ((size_t)(b * 64 + (n0 >> 6)) * 256 + c) * 128;
            #pragma unroll
            for (int jn = 0; jn < 4; ++jn) {
                f32x4 a = acc[tm][jn];
                u32x2 pk;
                pk.x = packbf(a[0] + bc, a[1] + bc);
                pk.y = packbf(a[2] + bc, a[3] + bc);
                *(u32x2*)(vrow + ((32 * jn + 8 * g) ^ sx)) = pk;
            }
        }
    }
}

// ---------------------------------------------------------------------------
// Fused attention, pipelined: raw barriers + counted vmcnt (no full drains).
// Per chunk: QK+exp+P(write) | vmcnt(12), barrier | PV(ds_read+MFMA) |
//            lgkm(0), barrier | issue DMA(n+2) into the buffer just read.
// grid = 512 (b = blk&7 XCD-affine), 256 threads (4 waves: 32q x 128c each)
// LDS: buf0 32KB | buf1 32KB | P 4x4KB  = 80 KiB -> 2 blocks/CU
// ---------------------------------------------------------------------------
__global__ __launch_bounds__(256) void attn_kernel(
    const float* __restrict__ x,
    const ushort_t* __restrict__ Qb, const ushort_t* __restrict__ Kb,
    const ushort_t* __restrict__ Vt,
    const float* __restrict__ gamma, float* __restrict__ out)
{
    __shared__ __align__(16) unsigned char smem[81920];

    const int b  = blockIdx.x & 7;
    const int n0 = (blockIdx.x >> 3) << 6;
    const int t  = threadIdx.x;
    const int l  = t & 63, w = t >> 6;
    const int li = l & 15, g = l >> 4;
    const int hq = w & 1,  hc = w >> 1;
    const int sx = (li & 7) << 4;
    unsigned char* Pw = smem + 65536 + w * 4096;

    // Q fragments (B-role: col=li -> q = n0+32hq+16jq+li); pre-scaled by log2e
    short8 qf[2];
    #pragma unroll
    for (int jq = 0; jq < 2; ++jq)
        qf[jq] = *(const short8*)(Qb + (size_t)(b * N_ + n0 + 32 * hq + 16 * jq + li) * CQK_ + 8 * g);

    f32x4 acc[2][8];
    #pragma unroll
    for (int i = 0; i < 2; ++i)
        #pragma unroll
        for (int j = 0; j < 8; ++j) acc[i][j] = (f32x4){0.f, 0.f, 0.f, 0.f};
    float rs[2] = {0.f, 0.f};

    const ushort_t* Kbb = Kb + (size_t)(b * N_) * CQK_;
    const char* Vtb = (const char*)Vt + (size_t)b * 64 * 32768;
    const f32x4 zf = {0.f, 0.f, 0.f, 0.f};

    short8 kfA[4], kfB[4];

    // ---- prologue: K(0)->kfA, K(1)->kfB, DMA(0)->buf0, DMA(1)->buf1 ----
    #pragma unroll
    for (int jm = 0; jm < 4; ++jm) {
        kfA[jm] = *(const short8*)(Kbb + (size_t)(16 * jm + li) * CQK_ + 8 * g);
        kfB[jm] = *(const short8*)(Kbb + (size_t)(64 + 16 * jm + li) * CQK_ + 8 * g);
    }
    {
        const char* gsrc = Vtb + t * 16;
        #pragma unroll
        for (int i = 0; i < 8; ++i) {
            __builtin_amdgcn_global_load_lds(
                (const __attribute__((address_space(1))) unsigned int*)(gsrc + i * 4096),
                (__attribute__((address_space(3))) unsigned int*)(smem + t * 16 + i * 4096),
                16, 0, 0);
            __builtin_amdgcn_global_load_lds(
                (const __attribute__((address_space(1))) unsigned int*)(gsrc + 32768 + i * 4096),
                (__attribute__((address_space(3))) unsigned int*)(smem + 32768 + t * 16 + i * 4096),
                16, 0, 0);
        }
    }

#define CHUNK_BODY(MC, BUFR, KFC)                                               \
    {                                                                           \
        /* 1. QK + exp2 + pack + P write (wave-private, no barrier needed) */   \
        _Pragma("unroll")                                                       \
        for (int jm = 0; jm < 4; ++jm) {                                        \
            _Pragma("unroll")                                                   \
            for (int jq = 0; jq < 2; ++jq) {                                    \
                f32x4 s = __builtin_amdgcn_mfma_f32_16x16x32_bf16(              \
                              KFC[jm], qf[jq], zf, 0, 0, 0);                    \
                float e0 = exp2f(s[0]), e1 = exp2f(s[1]);                       \
                float e2 = exp2f(s[2]), e3 = exp2f(s[3]);                       \
                rs[jq] += (e0 + e1) + (e2 + e3);                                \
                u32x2 pk; pk.x = cvtpk(e0, e1); pk.y = cvtpk(e2, e3);           \
                *(u32x2*)(Pw + (16 * jq + li) * 128                             \
                             + ((32 * jm + 8 * g) ^ sx)) = pk;                  \
            }                                                                   \
        }                                                                       \
        /* 2. prefetch K(n+2) into the regs QK just consumed */                 \
        {                                                                       \
            const int mk = ((MC) + 2) & 63;                                     \
            _Pragma("unroll")                                                   \
            for (int jm = 0; jm < 4; ++jm)                                      \
                KFC[jm] = *(const short8*)(Kbb                                  \
                    + (size_t)(64 * mk + 16 * jm + li) * CQK_ + 8 * g);         \
        }                                                                       \
        /* 3-4. counted wait: my DMA(n) retired (K(n+2)=4 + DMA(n+1)=8 stay */  \
        /*      in flight); barrier makes buf(n) valid block-wide */            \
        asm volatile("s_waitcnt vmcnt(12)" ::: "memory");                       \
        __builtin_amdgcn_s_barrier();                                           \
        __builtin_amdgcn_sched_barrier(0);                                      \
        /* 5. PV: A = P, B = V chunk (swizzled ds_read_b128) */                 \
        _Pragma("unroll")                                                       \
        for (int kb = 0; kb < 2; ++kb) {                                        \
            short8 pa[2], vb[8];                                                \
            _Pragma("unroll")                                                   \
            for (int jq = 0; jq < 2; ++jq)                                      \
                pa[jq] = *(const short8*)(Pw + (16 * jq + li) * 128             \
                                             + ((64 * kb + 16 * g) ^ sx));      \
            _Pragma("unroll")                                                   \
            for (int jc = 0; jc < 8; ++jc)                                      \
                vb[jc] = *(const short8*)((BUFR)                                \
                             + (128 * hc + 16 * jc + li) * 128                  \
                             + ((64 * kb + 16 * g) ^ sx));                      \
            _Pragma("unroll")                                                   \
            for (int jq = 0; jq < 2; ++jq)                                      \
                _Pragma("unroll")                                               \
                for (int jc = 0; jc < 8; ++jc)                                  \
                    acc[jq][jc] = __builtin_amdgcn_mfma_f32_16x16x32_bf16(      \
                                      pa[jq], vb[jc], acc[jq][jc], 0, 0, 0);    \
        }                                                                       \
        /* 6-7. my LDS reads retired; barrier -> buffer free block-wide */      \
        asm volatile("s_waitcnt lgkmcnt(0)" ::: "memory");                      \
        __builtin_amdgcn_s_barrier();                                           \
        __builtin_amdgcn_sched_barrier(0);                                      \
        /* 8. DMA chunk n+2 into the buffer just consumed (no drain) */         \
        {                                                                       \
            const int mv = ((MC) + 2) & 63;                                     \
            const char* gsrc = Vtb + (size_t)mv * 32768 + t * 16;               \
            _Pragma("unroll")                                                   \
            for (int i = 0; i < 8; ++i)                                         \
                __builtin_amdgcn_global_load_lds(                               \
                    (const __attribute__((address_space(1))) unsigned int*)(gsrc + i * 4096), \
                    (__attribute__((address_space(3))) unsigned int*)((BUFR) + t * 16 + i * 4096), \
                    16, 0, 0);                                                  \
        }                                                                       \
    }

    for (int mc = 0; mc < 64; mc += 2) {
        CHUNK_BODY(mc,     smem,         kfA)
        CHUNK_BODY(mc + 1, smem + 32768, kfB)
    }
#undef CHUNK_BODY

    // ---- softmax denominator: reduce over g-groups, redistribute ----
    #pragma unroll
    for (int jq = 0; jq < 2; ++jq) {
        rs[jq] += __shfl_xor(rs[jq], 16, 64);
        rs[jq] += __shfl_xor(rs[jq], 32, 64);
    }
    float inv[2][4];
    #pragma unroll
    for (int jq = 0; jq < 2; ++jq)
        #pragma unroll
        for (int r = 0; r < 4; ++r) {
            int v = __builtin_amdgcn_ds_bpermute((4 * g + r) * 4,
                                                 __float_as_int(rs[jq]));
            inv[jq][r] = 1.0f / __int_as_float(v);
        }

    const float gm = gamma[0];
    #pragma unroll
    for (int jq = 0; jq < 2; ++jq)
        #pragma unroll
        for (int jc = 0; jc < 8; ++jc) {
            const int c = 128 * hc + 16 * jc + li;
            const size_t rowoff = (size_t)(b * C_ + c) * N_
                                + n0 + 32 * hq + 16 * jq + 4 * g;
            float4 xv = *(const float4*)(x + rowoff);
            f32x4 a = acc[jq][jc];
            float4 o;
            o.x = gm * a[0] * inv[jq][0] + xv.x;
            o.y = gm * a[1] * inv[jq][1] + xv.y;
            o.z = gm * a[2] * inv[jq][2] + xv.z;
            o.w = gm * a[3] * inv[jq][3] + xv.w;
            *(float4*)(out + rowoff) = o;
        }
}

// ---------------------------------------------------------------------------
extern "C" void kernel_launch(void* const* d_in, const int* in_sizes, int n_in,
                              void* d_out, int out_size, void* d_ws, size_t ws_size,
                              hipStream_t stream)
{
    const float* x     = (const float*)d_in[0];
    const float* Wq    = (const float*)d_in[1];
    const float* bq    = (const float*)d_in[2];
    const float* Wk    = (const float*)d_in[3];
    const float* bk    = (const float*)d_in[4];
    const float* Wv    = (const float*)d_in[5];
    const float* bv    = (const float*)d_in[6];
    const float* gamma = (const float*)d_in[7];
    float* out = (float*)d_out;

    ushort_t* ws = (ushort_t*)d_ws;
    ushort_t* Qb   = ws;                                  // B*N*32 bf16
    ushort_t* Kb   = Qb + (size_t)B_ * N_ * CQK_;         // B*N*32 bf16
    ushort_t* Vt   = Kb + (size_t)B_ * N_ * CQK_;         // B*64 chunks * 32KB
    ushort_t* Wall = Vt + (size_t)B_ * C_ * N_;           // 320*256 bf16
    float*    ball = (float*)(Wall + (size_t)320 * C_);   // 320 f32

    prep_kernel<<<320, 256, 0, stream>>>(Wq, bq, Wk, bk, Wv, bv, Wall, ball);
    proj_kernel<<<B_ * (N_ / 64), 256, 0, stream>>>(x, Wall, ball, Qb, Kb, Vt);
    attn_kernel<<<B_ * (N_ / 64), 256, 0, stream>>>(x, Qb, Kb, Vt, gamma, out);
}

// Round 8
// 226.428 us; speedup vs baseline: 1.0226x; 1.0226x over previous
//
#include <hip/hip_runtime.h>

static constexpr int B_   = 8;
static constexpr int C_   = 256;
static constexpr int CQK_ = 32;
static constexpr int N_   = 4096;   // 64*64

typedef __attribute__((ext_vector_type(4))) float f32x4;
typedef __attribute__((ext_vector_type(8))) short short8;
typedef __attribute__((ext_vector_type(2))) unsigned int u32x2;
typedef unsigned short ushort_t;

// round-to-nearest-even fp32 -> bf16
__device__ inline unsigned short f2bf(float f) {
    unsigned u = __float_as_uint(f);
    return (unsigned short)((u + 0x7FFFu + ((u >> 16) & 1u)) >> 16);
}
__device__ inline unsigned packbf(float lo, float hi) {
    return (unsigned)f2bf(lo) | ((unsigned)f2bf(hi) << 16);
}
// packed f32->bf16 pair, single VOP3 (validated r6)
__device__ inline unsigned cvtpk(float lo, float hi) {
    unsigned r;
    asm("v_cvt_pk_bf16_f32 %0, %1, %2" : "=v"(r) : "v"(lo), "v"(hi));
    return r;
}

// proj x-tile swizzle (validated r3-r6)
__device__ inline int swzbits(int m) {
    return ((m & 3) << 5) | (((m >> 3) & 1) << 4);
}

template <int OFF>
__device__ inline u32x2 tr8(unsigned a) {
    u32x2 d;
    asm volatile("ds_read_b64_tr_b16 %0, %1 offset:%2"
                 : "=v"(d) : "v"(a), "i"(OFF));
    return d;
}

__device__ inline short8 mk8(u32x2 lo, u32x2 hi) {
    union { unsigned u[4]; short8 s; } v;
    v.u[0] = lo.x; v.u[1] = lo.y; v.u[2] = hi.x; v.u[3] = hi.y;
    return v.s;
}

// ---------------------------------------------------------------------------
// prep: weights -> bf16 (Wq pre-scaled by log2e), biases -> f32
// ---------------------------------------------------------------------------
__global__ __launch_bounds__(256) void prep_kernel(
    const float* __restrict__ Wq, const float* __restrict__ bq,
    const float* __restrict__ Wk, const float* __restrict__ bk,
    const float* __restrict__ Wv, const float* __restrict__ bv,
    ushort_t* __restrict__ Wall, float* __restrict__ ball)
{
    const int r = blockIdx.x;
    const int t = threadIdx.x;
    const float LOG2E = 1.4426950408889634f;
    const float* src;
    float bsrc, sc;
    if (r < 32)      { src = Wq + (size_t)r * C_;        bsrc = bq[r];      sc = LOG2E; }
    else if (r < 64) { src = Wk + (size_t)(r - 32) * C_; bsrc = bk[r - 32]; sc = 1.0f; }
    else             { src = Wv + (size_t)(r - 64) * C_; bsrc = bv[r - 64]; sc = 1.0f; }
    Wall[(size_t)r * C_ + t] = f2bf(src[t] * sc);
    if (t == 0) ball[r] = bsrc * sc;
}

// ---------------------------------------------------------------------------
// Projection via MFMA (structure validated r3-r6).
//  tm==0 (Q/K): C[oc][n] -> Qb/Kb row-major [n][ck]
//  tm>=1 (V):   C[n][oc] -> Vt 32-m chunks: byte =
//    (b*128 + m/32)*16384 + c*64 + ((2*(m&31)) ^ (((c>>1)&3)<<4))
// grid = 512 blocks (b = blk&7, XCD-affine), 256 threads (4 waves)
// ---------------------------------------------------------------------------
__global__ __launch_bounds__(256) void proj_kernel(
    const float* __restrict__ x,
    const ushort_t* __restrict__ Wall, const float* __restrict__ ball,
    ushort_t* __restrict__ Qb, ushort_t* __restrict__ Kb, ushort_t* __restrict__ Vt)
{
    __shared__ __align__(16) unsigned char xs[C_ * 128];   // 32 KB: [c][64n] bf16
    typedef __attribute__((address_space(3))) unsigned char lds_byte;
    const unsigned sbase = (unsigned)(size_t)(lds_byte*)xs;

    const int b  = blockIdx.x & 7;
    const int n0 = (blockIdx.x >> 3) << 6;
    const int t  = threadIdx.x;

    {
        const int cst = t >> 4;
        const int n4  = (t & 15) << 2;
        const float* xb = x + (size_t)b * C_ * N_ + n0;
        #pragma unroll
        for (int i = 0; i < 16; ++i) {
            const int c = 16 * i + cst;
            float4 v = *(const float4*)(xb + (size_t)c * N_ + n4);
            u32x2 pk;
            pk.x = packbf(v.x, v.y);
            pk.y = packbf(v.z, v.w);
            *(u32x2*)(xs + c * 128 + ((n4 * 2) ^ swzbits(c))) = pk;
        }
    }
    __syncthreads();

    const int l  = t & 63, w = t >> 6;
    const int li = l & 15, g = l >> 4;
    const int rr = li >> 2, ss = l & 3;
    const int swz_tr = (rr << 5) | ((g & 1) << 4);

    f32x4 acc[5][4];
    #pragma unroll
    for (int i = 0; i < 5; ++i)
        #pragma unroll
        for (int j = 0; j < 4; ++j) acc[i][j] = (f32x4){0.f, 0.f, 0.f, 0.f};

    #pragma unroll 2
    for (int kg = 0; kg < 8; ++kg) {
        u32x2 pb[4][2];
        #pragma unroll
        for (int jn = 0; jn < 4; ++jn) {
            unsigned a = sbase + (32 * kg + 8 * g + rr) * 128
                       + ((32 * jn + 8 * ss) ^ swz_tr);
            pb[jn][0] = tr8<0>(a);
            pb[jn][1] = tr8<512>(a);
        }
        short8 af[5];
        #pragma unroll
        for (int tm = 0; tm < 5; ++tm)
            af[tm] = *(const short8*)(Wall + (size_t)(16 * (4 * tm + w) + li) * C_
                                      + 32 * kg + 8 * g);
        asm volatile("s_waitcnt lgkmcnt(0)" ::: "memory");
        __builtin_amdgcn_sched_barrier(0);
        #pragma unroll
        for (int jn = 0; jn < 4; ++jn) {
            short8 Bf = mk8(pb[jn][0], pb[jn][1]);
            acc[0][jn] = __builtin_amdgcn_mfma_f32_16x16x32_bf16(
                             af[0], Bf, acc[0][jn], 0, 0, 0);
            #pragma unroll
            for (int tm = 1; tm < 5; ++tm)
                acc[tm][jn] = __builtin_amdgcn_mfma_f32_16x16x32_bf16(
                                  Bf, af[tm], acc[tm][jn], 0, 0, 0);
        }
    }

    // ---- epilogue ----
    {
        const int oc0 = 16 * w + 4 * g;
        float4 bias = *(const float4*)(ball + oc0);
        ushort_t* dst = (w < 2) ? Qb : Kb;
        const int col = (w < 2) ? oc0 : (oc0 - 32);
        #pragma unroll
        for (int jn = 0; jn < 4; ++jn) {
            const int n = n0 + 16 * jn + li;
            f32x4 a = acc[0][jn];
            u32x2 pk;
            pk.x = packbf(a[0] + bias.x, a[1] + bias.y);
            pk.y = packbf(a[2] + bias.z, a[3] + bias.w);
            *(u32x2*)(dst + (size_t)(b * N_ + n) * CQK_ + col) = pk;
        }
    }
    // V: lane holds (n = n0+16jn+4g+r, c = 16(4tm+w)+li-64)
    #pragma unroll
    for (int tm = 1; tm < 5; ++tm) {
        const int c  = 16 * (4 * tm + w) + li - 64;
        const float bc = ball[64 + c];
        const int sxc = ((c >> 1) & 3) << 4;
        #pragma unroll
        for (int jn = 0; jn < 4; ++jn) {
            const int ch = (n0 >> 5) + (jn >> 1);          // 32-m chunk index
            const int mcol = 32 * (jn & 1) + 8 * g;        // byte col 2*(m&31)
            f32x4 a = acc[tm][jn];
            u32x2 pk;
            pk.x = packbf(a[0] + bc, a[1] + bc);
            pk.y = packbf(a[2] + bc, a[3] + bc);
            char* dst = (char*)Vt + (size_t)(b * 128 + ch) * 16384
                      + c * 64 + (mcol ^ sxc);
            *(u32x2*)dst = pk;
        }
    }
}

// ---------------------------------------------------------------------------
// Fused attention, BARRIER-FREE. Wave = 64q x 64c (c-quarter = wave id).
// Per 32-m chunk: S^T = mfma_16x16x32(K,Q) -> exp2 -> cvt_pk -> wave-private
// P LDS [64q][32m] -> PV = mfma_16x16x32(P-frag, V-frag) from wave-private
// triple-buffered V LDS. Counted per-wave vmcnt only; zero __syncthreads.
// LDS: 4 waves * (3*4KB V + 4KB P) = 64 KB -> 2 blocks/CU.
// ---------------------------------------------------------------------------
__global__ __launch_bounds__(256) void attn_kernel(
    const float* __restrict__ x,
    const ushort_t* __restrict__ Qb, const ushort_t* __restrict__ Kb,
    const ushort_t* __restrict__ Vt,
    const float* __restrict__ gamma, float* __restrict__ out)
{
    __shared__ __align__(16) unsigned char smem[65536];

    const int b  = blockIdx.x & 7;
    const int n0 = (blockIdx.x >> 3) << 6;
    const int t  = threadIdx.x;
    const int l  = t & 63, w = t >> 6;
    const int li = l & 15, g = l >> 4;
    const int sxv = ((li >> 1) & 3) << 4;     // V row-swizzle (row = c)
    const int sxp = (li & 3) << 4;            // P row-swizzle (row = q)
    unsigned char* wlds = smem + w * 12288;   // 3 x 4 KB private V buffers
    unsigned char* Pw   = smem + 49152 + w * 4096;  // 4 KB private P

    // Q fragments: q = n0+16jq+li, k = 8g..8g+7 (B-operand of QK)
    short8 qf[4];
    #pragma unroll
    for (int jq = 0; jq < 4; ++jq)
        qf[jq] = *(const short8*)(Qb + (size_t)(b * N_ + n0 + 16 * jq + li) * CQK_ + 8 * g);

    f32x4 acc[4][4];
    #pragma unroll
    for (int i = 0; i < 4; ++i)
        #pragma unroll
        for (int j = 0; j < 4; ++j) acc[i][j] = (f32x4){0.f, 0.f, 0.f, 0.f};
    float rs[4] = {0.f, 0.f, 0.f, 0.f};

    const ushort_t* Kbb = Kb + (size_t)(b * N_) * CQK_;
    const char* Vgb = (const char*)Vt + (size_t)b * 128 * 16384 + w * 4096;
    const f32x4 zf = {0.f, 0.f, 0.f, 0.f};

    short8 kfA[2], kfB[2];

    // ---- prologue: K(0) -> kfA, DMA chunks 0,1 -> bufs 0,1 ----
    #pragma unroll
    for (int jm = 0; jm < 2; ++jm)
        kfA[jm] = *(const short8*)(Kbb + (size_t)(16 * jm + li) * CQK_ + 8 * g);
    #pragma unroll
    for (int i = 0; i < 4; ++i) {
        __builtin_amdgcn_global_load_lds(
            (const __attribute__((address_space(1))) unsigned int*)(Vgb + l * 16 + i * 1024),
            (__attribute__((address_space(3))) unsigned int*)(wlds + l * 16 + i * 1024),
            16, 0, 0);
        __builtin_amdgcn_global_load_lds(
            (const __attribute__((address_space(1))) unsigned int*)(Vgb + 16384 + l * 16 + i * 1024),
            (__attribute__((address_space(3))) unsigned int*)(wlds + 4096 + l * 16 + i * 1024),
            16, 0, 0);
    }
    int vsel = 0;

#define CHUNK_BODY(CH, KFC, KFN)                                                \
    {                                                                           \
        /* 1. K(n+1) prefetch */                                                \
        const int chn = ((CH) + 1) & 127;                                       \
        _Pragma("unroll")                                                       \
        for (int jm = 0; jm < 2; ++jm)                                          \
            KFN[jm] = *(const short8*)(Kbb                                      \
                + (size_t)(32 * chn + 16 * jm + li) * CQK_ + 8 * g);            \
        /* 2. DMA chunk n+2 into free wave-private buffer */                    \
        {                                                                       \
            const int chd = ((CH) + 2) & 127;                                   \
            int wsel = vsel + 2; if (wsel >= 3) wsel -= 3;                      \
            const char* gsrc = Vgb + (size_t)chd * 16384 + l * 16;              \
            unsigned char* ldst = wlds + wsel * 4096 + l * 16;                  \
            _Pragma("unroll")                                                   \
            for (int i = 0; i < 4; ++i)                                         \
                __builtin_amdgcn_global_load_lds(                               \
                    (const __attribute__((address_space(1))) unsigned int*)(gsrc + i * 1024), \
                    (__attribute__((address_space(3))) unsigned int*)(ldst + i * 1024), \
                    16, 0, 0);                                                  \
        }                                                                       \
        /* 3. S^T = K Q (16x16x32), exp2, cvt_pk -> wave-private P LDS */       \
        _Pragma("unroll")                                                       \
        for (int jm = 0; jm < 2; ++jm) {                                        \
            _Pragma("unroll")                                                   \
            for (int jq = 0; jq < 4; ++jq) {                                    \
                f32x4 s = __builtin_amdgcn_mfma_f32_16x16x32_bf16(              \
                              KFC[jm], qf[jq], zf, 0, 0, 0);                    \
                float e0 = exp2f(s[0]), e1 = exp2f(s[1]);                       \
                float e2 = exp2f(s[2]), e3 = exp2f(s[3]);                       \
                rs[jq] += (e0 + e1) + (e2 + e3);                                \
                u32x2 pk; pk.x = cvtpk(e0, e1); pk.y = cvtpk(e2, e3);           \
                *(u32x2*)(Pw + (16 * jq + li) * 64                              \
                             + ((32 * jm + 8 * g) ^ sxp)) = pk;                 \
            }                                                                   \
        }                                                                       \
        /* 4. P writes done (lgkm) + my DMA(n) retired (vmcnt counted) */       \
        asm volatile("s_waitcnt vmcnt(10) lgkmcnt(0)" ::: "memory");            \
        __builtin_amdgcn_sched_barrier(0);                                      \
        /* 5. PV: A = P-frag, B = V-frag, both b128 wave-private reads */       \
        {                                                                       \
            const unsigned char* vb = wlds + vsel * 4096;                       \
            short8 pa[4], vv[4];                                                \
            _Pragma("unroll")                                                   \
            for (int jq = 0; jq < 4; ++jq)                                      \
                pa[jq] = *(const short8*)(Pw + (16 * jq + li) * 64              \
                                             + ((16 * g) ^ sxp));               \
            _Pragma("unroll")                                                   \
            for (int jc = 0; jc < 4; ++jc)                                      \
                vv[jc] = *(const short8*)(vb + (16 * jc + li) * 64              \
                                             + ((16 * g) ^ sxv));               \
            _Pragma("unroll")                                                   \
            for (int jq = 0; jq < 4; ++jq)                                      \
                _Pragma("unroll")                                               \
                for (int jc = 0; jc < 4; ++jc)                                  \
                    acc[jq][jc] = __builtin_amdgcn_mfma_f32_16x16x32_bf16(      \
                                      pa[jq], vv[jc], acc[jq][jc], 0, 0, 0);    \
        }                                                                       \
        vsel = (vsel == 2) ? 0 : vsel + 1;                                      \
    }

    for (int mc = 0; mc < 128; mc += 2) {
        CHUNK_BODY(mc,     kfA, kfB)
        CHUNK_BODY(mc + 1, kfB, kfA)
    }
#undef CHUNK_BODY

    // ---- softmax denominator: sum over g-groups, redistribute ----
    #pragma unroll
    for (int jq = 0; jq < 4; ++jq) {
        rs[jq] += __shfl_xor(rs[jq], 16, 64);
        rs[jq] += __shfl_xor(rs[jq], 32, 64);
    }
    float inv[4][4];
    #pragma unroll
    for (int jq = 0; jq < 4; ++jq)
        #pragma unroll
        for (int r = 0; r < 4; ++r) {
            int v = __builtin_amdgcn_ds_bpermute((4 * g + r) * 4,
                                                 __float_as_int(rs[jq]));
            inv[jq][r] = 1.0f / __int_as_float(v);
        }

    const float gm = gamma[0];
    #pragma unroll
    for (int jq = 0; jq < 4; ++jq)
        #pragma unroll
        for (int jc = 0; jc < 4; ++jc) {
            const int c = 64 * w + 16 * jc + li;
            const size_t rowoff = (size_t)(b * C_ + c) * N_ + n0 + 16 * jq + 4 * g;
            float4 xv = *(const float4*)(x + rowoff);
            f32x4 a = acc[jq][jc];
            float4 o;
            o.x = gm * a[0] * inv[jq][0] + xv.x;
            o.y = gm * a[1] * inv[jq][1] + xv.y;
            o.z = gm * a[2] * inv[jq][2] + xv.z;
            o.w = gm * a[3] * inv[jq][3] + xv.w;
            *(float4*)(out + rowoff) = o;
        }
}

// ---------------------------------------------------------------------------
extern "C" void kernel_launch(void* const* d_in, const int* in_sizes, int n_in,
                              void* d_out, int out_size, void* d_ws, size_t ws_size,
                              hipStream_t stream)
{
    const float* x     = (const float*)d_in[0];
    const float* Wq    = (const float*)d_in[1];
    const float* bq    = (const float*)d_in[2];
    const float* Wk    = (const float*)d_in[3];
    const float* bk    = (const float*)d_in[4];
    const float* Wv    = (const float*)d_in[5];
    const float* bv    = (const float*)d_in[6];
    const float* gamma = (const float*)d_in[7];
    float* out = (float*)d_out;

    ushort_t* ws = (ushort_t*)d_ws;
    ushort_t* Qb   = ws;                                  // B*N*32 bf16
    ushort_t* Kb   = Qb + (size_t)B_ * N_ * CQK_;         // B*N*32 bf16
    ushort_t* Vt   = Kb + (size_t)B_ * N_ * CQK_;         // B*128 chunks * 16KB
    ushort_t* Wall = Vt + (size_t)B_ * C_ * N_;           // 320*256 bf16
    float*    ball = (float*)(Wall + (size_t)320 * C_);   // 320 f32

    prep_kernel<<<320, 256, 0, stream>>>(Wq, bq, Wk, bk, Wv, bv, Wall, ball);
    proj_kernel<<<B_ * (N_ / 64), 256, 0, stream>>>(x, Wall, ball, Qb, Kb, Vt);
    attn_kernel<<<B_ * (N_ / 64), 256, 0, stream>>>(x, Qb, Kb, Vt, gamma, out);
}

// Round 9
// 180.490 us; speedup vs baseline: 1.2829x; 1.2545x over previous
//
#include <hip/hip_runtime.h>

static constexpr int B_   = 8;
static constexpr int C_   = 256;
static constexpr int CQK_ = 32;
static constexpr int N_   = 4096;   // 64*64

typedef __attribute__((ext_vector_type(4))) float f32x4;
typedef __attribute__((ext_vector_type(8))) short short8;
typedef __attribute__((ext_vector_type(2))) unsigned int u32x2;
typedef unsigned short ushort_t;

// round-to-nearest-even fp32 -> bf16
__device__ inline unsigned short f2bf(float f) {
    unsigned u = __float_as_uint(f);
    return (unsigned short)((u + 0x7FFFu + ((u >> 16) & 1u)) >> 16);
}
__device__ inline unsigned packbf(float lo, float hi) {
    return (unsigned)f2bf(lo) | ((unsigned)f2bf(hi) << 16);
}
// packed f32->bf16 pair, single VOP3 (validated r6)
__device__ inline unsigned cvtpk(float lo, float hi) {
    unsigned r;
    asm("v_cvt_pk_bf16_f32 %0, %1, %2" : "=v"(r) : "v"(lo), "v"(hi));
    return r;
}

// proj x-tile swizzle (validated r3-r8)
__device__ inline int swzbits(int m) {
    return ((m & 3) << 5) | (((m >> 3) & 1) << 4);
}

template <int OFF>
__device__ inline u32x2 tr8(unsigned a) {
    u32x2 d;
    asm volatile("ds_read_b64_tr_b16 %0, %1 offset:%2"
                 : "=v"(d) : "v"(a), "i"(OFF));
    return d;
}

__device__ inline short8 mk8(u32x2 lo, u32x2 hi) {
    union { unsigned u[4]; short8 s; } v;
    v.u[0] = lo.x; v.u[1] = lo.y; v.u[2] = hi.x; v.u[3] = hi.y;
    return v.s;
}

// ---------------------------------------------------------------------------
// prep: weights -> bf16 (Wq pre-scaled by log2e), biases -> f32
// ---------------------------------------------------------------------------
__global__ __launch_bounds__(256) void prep_kernel(
    const float* __restrict__ Wq, const float* __restrict__ bq,
    const float* __restrict__ Wk, const float* __restrict__ bk,
    const float* __restrict__ Wv, const float* __restrict__ bv,
    ushort_t* __restrict__ Wall, float* __restrict__ ball)
{
    const int r = blockIdx.x;
    const int t = threadIdx.x;
    const float LOG2E = 1.4426950408889634f;
    const float* src;
    float bsrc, sc;
    if (r < 32)      { src = Wq + (size_t)r * C_;        bsrc = bq[r];      sc = LOG2E; }
    else if (r < 64) { src = Wk + (size_t)(r - 32) * C_; bsrc = bk[r - 32]; sc = 1.0f; }
    else             { src = Wv + (size_t)(r - 64) * C_; bsrc = bv[r - 64]; sc = 1.0f; }
    Wall[(size_t)r * C_ + t] = f2bf(src[t] * sc);
    if (t == 0) ball[r] = bsrc * sc;
}

// ---------------------------------------------------------------------------
// Projection via MFMA (r5-validated version, incl. the 64-m-chunk V image:
//   byte = ((b*64 + m/64)*256 + c)*128 + ((2*(m&63)) ^ ((c&7)<<4)) )
// grid = 512 blocks (b = blk&7, XCD-affine), 256 threads (4 waves)
// ---------------------------------------------------------------------------
__global__ __launch_bounds__(256) void proj_kernel(
    const float* __restrict__ x,
    const ushort_t* __restrict__ Wall, const float* __restrict__ ball,
    ushort_t* __restrict__ Qb, ushort_t* __restrict__ Kb, ushort_t* __restrict__ Vt)
{
    __shared__ __align__(16) unsigned char xs[C_ * 128];   // 32 KB: [c][64n] bf16
    typedef __attribute__((address_space(3))) unsigned char lds_byte;
    const unsigned sbase = (unsigned)(size_t)(lds_byte*)xs;

    const int b  = blockIdx.x & 7;
    const int n0 = (blockIdx.x >> 3) << 6;
    const int t  = threadIdx.x;

    {
        const int cst = t >> 4;
        const int n4  = (t & 15) << 2;
        const float* xb = x + (size_t)b * C_ * N_ + n0;
        #pragma unroll
        for (int i = 0; i < 16; ++i) {
            const int c = 16 * i + cst;
            float4 v = *(const float4*)(xb + (size_t)c * N_ + n4);
            u32x2 pk;
            pk.x = packbf(v.x, v.y);
            pk.y = packbf(v.z, v.w);
            *(u32x2*)(xs + c * 128 + ((n4 * 2) ^ swzbits(c))) = pk;
        }
    }
    __syncthreads();

    const int l  = t & 63, w = t >> 6;
    const int li = l & 15, g = l >> 4;
    const int rr = li >> 2, ss = l & 3;
    const int swz_tr = (rr << 5) | ((g & 1) << 4);

    f32x4 acc[5][4];
    #pragma unroll
    for (int i = 0; i < 5; ++i)
        #pragma unroll
        for (int j = 0; j < 4; ++j) acc[i][j] = (f32x4){0.f, 0.f, 0.f, 0.f};

    #pragma unroll 2
    for (int kg = 0; kg < 8; ++kg) {
        u32x2 pb[4][2];
        #pragma unroll
        for (int jn = 0; jn < 4; ++jn) {
            unsigned a = sbase + (32 * kg + 8 * g + rr) * 128
                       + ((32 * jn + 8 * ss) ^ swz_tr);
            pb[jn][0] = tr8<0>(a);
            pb[jn][1] = tr8<512>(a);
        }
        short8 af[5];
        #pragma unroll
        for (int tm = 0; tm < 5; ++tm)
            af[tm] = *(const short8*)(Wall + (size_t)(16 * (4 * tm + w) + li) * C_
                                      + 32 * kg + 8 * g);
        asm volatile("s_waitcnt lgkmcnt(0)" ::: "memory");
        __builtin_amdgcn_sched_barrier(0);
        #pragma unroll
        for (int jn = 0; jn < 4; ++jn) {
            short8 Bf = mk8(pb[jn][0], pb[jn][1]);
            acc[0][jn] = __builtin_amdgcn_mfma_f32_16x16x32_bf16(
                             af[0], Bf, acc[0][jn], 0, 0, 0);
            #pragma unroll
            for (int tm = 1; tm < 5; ++tm)
                acc[tm][jn] = __builtin_amdgcn_mfma_f32_16x16x32_bf16(
                                  Bf, af[tm], acc[tm][jn], 0, 0, 0);
        }
    }

    // ---- epilogue ----
    {
        const int oc0 = 16 * w + 4 * g;
        float4 bias = *(const float4*)(ball + oc0);
        ushort_t* dst = (w < 2) ? Qb : Kb;
        const int col = (w < 2) ? oc0 : (oc0 - 32);
        #pragma unroll
        for (int jn = 0; jn < 4; ++jn) {
            const int n = n0 + 16 * jn + li;
            f32x4 a = acc[0][jn];
            u32x2 pk;
            pk.x = packbf(a[0] + bias.x, a[1] + bias.y);
            pk.y = packbf(a[2] + bias.z, a[3] + bias.w);
            *(u32x2*)(dst + (size_t)(b * N_ + n) * CQK_ + col) = pk;
        }
    }
    // V: lane holds (m' = 16jn+4g+r within 64-chunk, c) -> r5 image
    {
        const int sx = (li & 7) << 4;
        #pragma unroll
        for (int tm = 1; tm < 5; ++tm) {
            const int c  = 16 * (4 * tm + w) + li - 64;
            const float bc = ball[64 + c];
            char* vrow = (char*)Vt
                       + ((size_t)(b * 64 + (n0 >> 6)) * 256 + c) * 128;
            #pragma unroll
            for (int jn = 0; jn < 4; ++jn) {
                f32x4 a = acc[tm][jn];
                u32x2 pk;
                pk.x = packbf(a[0] + bc, a[1] + bc);
                pk.y = packbf(a[2] + bc, a[3] + bc);
                *(u32x2*)(vrow + ((32 * jn + 8 * g) ^ sx)) = pk;
            }
        }
    }
}

// ---------------------------------------------------------------------------
// Fused attention: dedup'd QK (wave w owns m-slice 16w of each 64-m chunk),
// shared P [64q][64m] (stride 128, (q&7)<<4 XOR), per-wave c-quarter PV,
// DMA double-buffered V, raw barriers + counted vmcnt(9) (never 0 in-loop).
// grid = 512 (b = blk&7 XCD-affine), 256 threads (4 waves)
// LDS: 2x32KB V | 8KB P | 1KB rsl = 74752 B -> 2 blocks/CU
// ---------------------------------------------------------------------------
__global__ __launch_bounds__(256) void attn_kernel(
    const float* __restrict__ x,
    const ushort_t* __restrict__ Qb, const ushort_t* __restrict__ Kb,
    const ushort_t* __restrict__ Vt,
    const float* __restrict__ gamma, float* __restrict__ out)
{
    __shared__ __align__(16) unsigned char smem[74752];

    const int b  = blockIdx.x & 7;
    const int n0 = (blockIdx.x >> 3) << 6;
    const int t  = threadIdx.x;
    const int l  = t & 63, w = t >> 6;
    const int li = l & 15, g = l >> 4;
    const int sx = (li & 7) << 4;
    unsigned char* Pl  = smem + 65536;
    float* rsl = (float*)(smem + 73728);      // [w][64q] partial rowsums

    // Q fragments (B-role: col=li -> q = n0+16jq+li, k = 8g..8g+7)
    short8 qf[4];
    #pragma unroll
    for (int jq = 0; jq < 4; ++jq)
        qf[jq] = *(const short8*)(Qb + (size_t)(b * N_ + n0 + 16 * jq + li) * CQK_ + 8 * g);

    f32x4 acc[4][4];
    #pragma unroll
    for (int i = 0; i < 4; ++i)
        #pragma unroll
        for (int j = 0; j < 4; ++j) acc[i][j] = (f32x4){0.f, 0.f, 0.f, 0.f};
    float rs[4] = {0.f, 0.f, 0.f, 0.f};

    const ushort_t* Kbb = Kb + (size_t)(b * N_) * CQK_;
    const char* Vtb = (const char*)Vt + (size_t)b * 64 * 32768;
    const f32x4 zf = {0.f, 0.f, 0.f, 0.f};

    short8 kfA, kfB;

    // ---- prologue: K(0)->kfA, K(1)->kfB, DMA(0)->buf0, DMA(1)->buf1 ----
    kfA = *(const short8*)(Kbb + (size_t)(16 * w + li) * CQK_ + 8 * g);
    kfB = *(const short8*)(Kbb + (size_t)(64 + 16 * w + li) * CQK_ + 8 * g);
    {
        const char* gsrc = Vtb + t * 16;
        #pragma unroll
        for (int i = 0; i < 8; ++i)
            __builtin_amdgcn_global_load_lds(
                (const __attribute__((address_space(1))) unsigned int*)(gsrc + i * 4096),
                (__attribute__((address_space(3))) unsigned int*)(smem + t * 16 + i * 4096),
                16, 0, 0);
        #pragma unroll
        for (int i = 0; i < 8; ++i)
            __builtin_amdgcn_global_load_lds(
                (const __attribute__((address_space(1))) unsigned int*)(gsrc + 32768 + i * 4096),
                (__attribute__((address_space(3))) unsigned int*)(smem + 32768 + t * 16 + i * 4096),
                16, 0, 0);
    }

#define CHUNK_BODY(MC, BUFR, KFC)                                               \
    {                                                                           \
        /* 1. QK for my 16-m slice (4 MFMA), exp2, write shared P */            \
        _Pragma("unroll")                                                       \
        for (int jq = 0; jq < 4; ++jq) {                                        \
            f32x4 s = __builtin_amdgcn_mfma_f32_16x16x32_bf16(                  \
                          KFC, qf[jq], zf, 0, 0, 0);                            \
            float e0 = exp2f(s[0]), e1 = exp2f(s[1]);                           \
            float e2 = exp2f(s[2]), e3 = exp2f(s[3]);                           \
            rs[jq] += (e0 + e1) + (e2 + e3);                                    \
            u32x2 pk; pk.x = cvtpk(e0, e1); pk.y = cvtpk(e2, e3);               \
            *(u32x2*)(Pl + (16 * jq + li) * 128                                 \
                         + ((32 * w + 8 * g) ^ sx)) = pk;                       \
        }                                                                       \
        /* 2. prefetch K(n+2) (1 load) */                                       \
        KFC = *(const short8*)(Kbb                                              \
              + (size_t)(64 * (((MC) + 2) & 63) + 16 * w + li) * CQK_ + 8 * g); \
        /* 3. P visible + DMA(n) retired; DMA(n+1)+K prefetches in flight */    \
        asm volatile("s_waitcnt vmcnt(9) lgkmcnt(0)" ::: "memory");             \
        __builtin_amdgcn_s_barrier();                                           \
        asm volatile("" ::: "memory");                                          \
        /* 4. PV: A = shared P, B = V (c-quarter 64w..64w+63) */                \
        _Pragma("unroll")                                                       \
        for (int kb = 0; kb < 2; ++kb) {                                        \
            short8 pa[4], vv[4];                                                \
            _Pragma("unroll")                                                   \
            for (int jq = 0; jq < 4; ++jq)                                      \
                pa[jq] = *(const short8*)(Pl + (16 * jq + li) * 128             \
                                             + ((64 * kb + 16 * g) ^ sx));      \
            _Pragma("unroll")                                                   \
            for (int jc = 0; jc < 4; ++jc)                                      \
                vv[jc] = *(const short8*)((BUFR)                                \
                             + (64 * w + 16 * jc + li) * 128                    \
                             + ((64 * kb + 16 * g) ^ sx));                      \
            _Pragma("unroll")                                                   \
            for (int jq = 0; jq < 4; ++jq)                                      \
                _Pragma("unroll")                                               \
                for (int jc = 0; jc < 4; ++jc)                                  \
                    acc[jq][jc] = __builtin_amdgcn_mfma_f32_16x16x32_bf16(      \
                                      pa[jq], vv[jc], acc[jq][jc], 0, 0, 0);    \
        }                                                                       \
        /* 5. my P/V reads retired; barrier -> P & buf free block-wide */       \
        asm volatile("s_waitcnt lgkmcnt(0)" ::: "memory");                      \
        __builtin_amdgcn_s_barrier();                                           \
        asm volatile("" ::: "memory");                                          \
        /* 6. DMA(n+2) into the buffer just consumed */                         \
        {                                                                       \
            const char* gsrc = Vtb + (size_t)(((MC) + 2) & 63) * 32768 + t * 16;\
            _Pragma("unroll")                                                   \
            for (int i = 0; i < 8; ++i)                                         \
                __builtin_amdgcn_global_load_lds(                               \
                    (const __attribute__((address_space(1))) unsigned int*)(gsrc + i * 4096), \
                    (__attribute__((address_space(3))) unsigned int*)((BUFR) + t * 16 + i * 4096), \
                    16, 0, 0);                                                  \
        }                                                                       \
    }

    for (int mc = 0; mc < 64; mc += 2) {
        CHUNK_BODY(mc,     smem,         kfA)
        CHUNK_BODY(mc + 1, smem + 32768, kfB)
    }
#undef CHUNK_BODY

    // ---- rowsums: wave-partial (sum over g) -> rsl -> cross-wave sum ----
    #pragma unroll
    for (int jq = 0; jq < 4; ++jq) {
        rs[jq] += __shfl_xor(rs[jq], 16, 64);
        rs[jq] += __shfl_xor(rs[jq], 32, 64);
    }
    if (g == 0) {
        #pragma unroll
        for (int jq = 0; jq < 4; ++jq)
            rsl[w * 64 + 16 * jq + li] = rs[jq];
    }
    __syncthreads();

    float inv[4][4];
    #pragma unroll
    for (int jq = 0; jq < 4; ++jq) {
        f32x4 v0 = *(const f32x4*)(rsl +   0 + 16 * jq + 4 * g);
        f32x4 v1 = *(const f32x4*)(rsl +  64 + 16 * jq + 4 * g);
        f32x4 v2 = *(const f32x4*)(rsl + 128 + 16 * jq + 4 * g);
        f32x4 v3 = *(const f32x4*)(rsl + 192 + 16 * jq + 4 * g);
        f32x4 sum = v0 + v1 + v2 + v3;
        #pragma unroll
        for (int r = 0; r < 4; ++r) inv[jq][r] = 1.0f / sum[r];
    }

    const float gm = gamma[0];
    #pragma unroll
    for (int jq = 0; jq < 4; ++jq)
        #pragma unroll
        for (int jc = 0; jc < 4; ++jc) {
            const int c = 64 * w + 16 * jc + li;
            const size_t rowoff = (size_t)(b * C_ + c) * N_ + n0 + 16 * jq + 4 * g;
            float4 xv = *(const float4*)(x + rowoff);
            f32x4 a = acc[jq][jc];
            float4 o;
            o.x = gm * a[0] * inv[jq][0] + xv.x;
            o.y = gm * a[1] * inv[jq][1] + xv.y;
            o.z = gm * a[2] * inv[jq][2] + xv.z;
            o.w = gm * a[3] * inv[jq][3] + xv.w;
            *(float4*)(out + rowoff) = o;
        }
}

// ---------------------------------------------------------------------------
extern "C" void kernel_launch(void* const* d_in, const int* in_sizes, int n_in,
                              void* d_out, int out_size, void* d_ws, size_t ws_size,
                              hipStream_t stream)
{
    const float* x     = (const float*)d_in[0];
    const float* Wq    = (const float*)d_in[1];
    const float* bq    = (const float*)d_in[2];
    const float* Wk    = (const float*)d_in[3];
    const float* bk    = (const float*)d_in[4];
    const float* Wv    = (const float*)d_in[5];
    const float* bv    = (const float*)d_in[6];
    const float* gamma = (const float*)d_in[7];
    float* out = (float*)d_out;

    ushort_t* ws = (ushort_t*)d_ws;
    ushort_t* Qb   = ws;                                  // B*N*32 bf16
    ushort_t* Kb   = Qb + (size_t)B_ * N_ * CQK_;         // B*N*32 bf16
    ushort_t* Vt   = Kb + (size_t)B_ * N_ * CQK_;         // B*64 chunks * 32KB
    ushort_t* Wall = Vt + (size_t)B_ * C_ * N_;           // 320*256 bf16
    float*    ball = (float*)(Wall + (size_t)320 * C_);   // 320 f32

    prep_kernel<<<320, 256, 0, stream>>>(Wq, bq, Wk, bk, Wv, bv, Wall, ball);
    proj_kernel<<<B_ * (N_ / 64), 256, 0, stream>>>(x, Wall, ball, Qb, Kb, Vt);
    attn_kernel<<<B_ * (N_ / 64), 256, 0, stream>>>(x, Qb, Kb, Vt, gamma, out);
}

// Round 10
// 150.551 us; speedup vs baseline: 1.5380x; 1.1989x over previous
//
#include <hip/hip_runtime.h>

static constexpr int B_   = 8;
static constexpr int C_   = 256;
static constexpr int CQK_ = 32;
static constexpr int N_   = 4096;   // 64*64

typedef __attribute__((ext_vector_type(4)))  float f32x4;
typedef __attribute__((ext_vector_type(16))) float f32x16;
typedef __attribute__((ext_vector_type(8)))  short short8;
typedef __attribute__((ext_vector_type(2)))  unsigned int u32x2;
typedef unsigned short ushort_t;

// round-to-nearest-even fp32 -> bf16
__device__ inline unsigned short f2bf(float f) {
    unsigned u = __float_as_uint(f);
    return (unsigned short)((u + 0x7FFFu + ((u >> 16) & 1u)) >> 16);
}
__device__ inline unsigned packbf(float lo, float hi) {
    return (unsigned)f2bf(lo) | ((unsigned)f2bf(hi) << 16);
}
// packed f32->bf16 pair, single VOP3 (validated r6+)
__device__ inline unsigned cvtpk(float lo, float hi) {
    unsigned r;
    asm("v_cvt_pk_bf16_f32 %0, %1, %2" : "=v"(r) : "v"(lo), "v"(hi));
    return r;
}
// raw transcendental exp2 (input = log2-domain; Q pre-scaled by log2e)
__device__ inline float vexp2(float x) {
    float r;
    asm("v_exp_f32 %0, %1" : "=v"(r) : "v"(x));
    return r;
}
// v_permlane32_swap_b32: a.hi <-> b.lo (both modified)
__device__ inline void plswap(unsigned& a, unsigned& b) {
    asm("v_permlane32_swap_b32 %0, %1" : "+v"(a), "+v"(b));
}

// proj x-tile swizzle (validated r3-r9)
__device__ inline int swzbits(int m) {
    return ((m & 3) << 5) | (((m >> 3) & 1) << 4);
}

template <int OFF>
__device__ inline u32x2 tr8(unsigned a) {
    u32x2 d;
    asm volatile("ds_read_b64_tr_b16 %0, %1 offset:%2"
                 : "=v"(d) : "v"(a), "i"(OFF));
    return d;
}

__device__ inline short8 mk8(u32x2 lo, u32x2 hi) {
    union { unsigned u[4]; short8 s; } v;
    v.u[0] = lo.x; v.u[1] = lo.y; v.u[2] = hi.x; v.u[3] = hi.y;
    return v.s;
}
__device__ inline short8 mk8u(unsigned a, unsigned b, unsigned c, unsigned d) {
    union { unsigned u[4]; short8 s; } v;
    v.u[0] = a; v.u[1] = b; v.u[2] = c; v.u[3] = d;
    return v.s;
}

// ---------------------------------------------------------------------------
// prep: weights -> bf16 (Wq pre-scaled by log2e), biases -> f32
// ---------------------------------------------------------------------------
__global__ __launch_bounds__(256) void prep_kernel(
    const float* __restrict__ Wq, const float* __restrict__ bq,
    const float* __restrict__ Wk, const float* __restrict__ bk,
    const float* __restrict__ Wv, const float* __restrict__ bv,
    ushort_t* __restrict__ Wall, float* __restrict__ ball)
{
    const int r = blockIdx.x;
    const int t = threadIdx.x;
    const float LOG2E = 1.4426950408889634f;
    const float* src;
    float bsrc, sc;
    if (r < 32)      { src = Wq + (size_t)r * C_;        bsrc = bq[r];      sc = LOG2E; }
    else if (r < 64) { src = Wk + (size_t)(r - 32) * C_; bsrc = bk[r - 32]; sc = 1.0f; }
    else             { src = Wv + (size_t)(r - 64) * C_; bsrc = bv[r - 64]; sc = 1.0f; }
    Wall[(size_t)r * C_ + t] = f2bf(src[t] * sc);
    if (t == 0) ball[r] = bsrc * sc;
}

// ---------------------------------------------------------------------------
// Projection via MFMA (r5/r9-validated, incl. the 64-m-chunk V image:
//   byte = ((b*64 + m/64)*256 + c)*128 + ((2*(m&63)) ^ ((c&7)<<4)) )
// grid = 512 blocks (b = blk&7, XCD-affine), 256 threads (4 waves)
// ---------------------------------------------------------------------------
__global__ __launch_bounds__(256) void proj_kernel(
    const float* __restrict__ x,
    const ushort_t* __restrict__ Wall, const float* __restrict__ ball,
    ushort_t* __restrict__ Qb, ushort_t* __restrict__ Kb, ushort_t* __restrict__ Vt)
{
    __shared__ __align__(16) unsigned char xs[C_ * 128];   // 32 KB: [c][64n] bf16
    typedef __attribute__((address_space(3))) unsigned char lds_byte;
    const unsigned sbase = (unsigned)(size_t)(lds_byte*)xs;

    const int b  = blockIdx.x & 7;
    const int n0 = (blockIdx.x >> 3) << 6;
    const int t  = threadIdx.x;

    {
        const int cst = t >> 4;
        const int n4  = (t & 15) << 2;
        const float* xb = x + (size_t)b * C_ * N_ + n0;
        #pragma unroll
        for (int i = 0; i < 16; ++i) {
            const int c = 16 * i + cst;
            float4 v = *(const float4*)(xb + (size_t)c * N_ + n4);
            u32x2 pk;
            pk.x = packbf(v.x, v.y);
            pk.y = packbf(v.z, v.w);
            *(u32x2*)(xs + c * 128 + ((n4 * 2) ^ swzbits(c))) = pk;
        }
    }
    __syncthreads();

    const int l  = t & 63, w = t >> 6;
    const int li = l & 15, g = l >> 4;
    const int rr = li >> 2, ss = l & 3;
    const int swz_tr = (rr << 5) | ((g & 1) << 4);

    f32x4 acc[5][4];
    #pragma unroll
    for (int i = 0; i < 5; ++i)
        #pragma unroll
        for (int j = 0; j < 4; ++j) acc[i][j] = (f32x4){0.f, 0.f, 0.f, 0.f};

    #pragma unroll 2
    for (int kg = 0; kg < 8; ++kg) {
        u32x2 pb[4][2];
        #pragma unroll
        for (int jn = 0; jn < 4; ++jn) {
            unsigned a = sbase + (32 * kg + 8 * g + rr) * 128
                       + ((32 * jn + 8 * ss) ^ swz_tr);
            pb[jn][0] = tr8<0>(a);
            pb[jn][1] = tr8<512>(a);
        }
        short8 af[5];
        #pragma unroll
        for (int tm = 0; tm < 5; ++tm)
            af[tm] = *(const short8*)(Wall + (size_t)(16 * (4 * tm + w) + li) * C_
                                      + 32 * kg + 8 * g);
        asm volatile("s_waitcnt lgkmcnt(0)" ::: "memory");
        __builtin_amdgcn_sched_barrier(0);
        #pragma unroll
        for (int jn = 0; jn < 4; ++jn) {
            short8 Bf = mk8(pb[jn][0], pb[jn][1]);
            acc[0][jn] = __builtin_amdgcn_mfma_f32_16x16x32_bf16(
                             af[0], Bf, acc[0][jn], 0, 0, 0);
            #pragma unroll
            for (int tm = 1; tm < 5; ++tm)
                acc[tm][jn] = __builtin_amdgcn_mfma_f32_16x16x32_bf16(
                                  Bf, af[tm], acc[tm][jn], 0, 0, 0);
        }
    }

    // ---- epilogue ----
    {
        const int oc0 = 16 * w + 4 * g;
        float4 bias = *(const float4*)(ball + oc0);
        ushort_t* dst = (w < 2) ? Qb : Kb;
        const int col = (w < 2) ? oc0 : (oc0 - 32);
        #pragma unroll
        for (int jn = 0; jn < 4; ++jn) {
            const int n = n0 + 16 * jn + li;
            f32x4 a = acc[0][jn];
            u32x2 pk;
            pk.x = packbf(a[0] + bias.x, a[1] + bias.y);
            pk.y = packbf(a[2] + bias.z, a[3] + bias.w);
            *(u32x2*)(dst + (size_t)(b * N_ + n) * CQK_ + col) = pk;
        }
    }
    {
        const int sx = (li & 7) << 4;
        #pragma unroll
        for (int tm = 1; tm < 5; ++tm) {
            const int c  = 16 * (4 * tm + w) + li - 64;
            const float bc = ball[64 + c];
            char* vrow = (char*)Vt
                       + ((size_t)(b * 64 + (n0 >> 6)) * 256 + c) * 128;
            #pragma unroll
            for (int jn = 0; jn < 4; ++jn) {
                f32x4 a = acc[tm][jn];
                u32x2 pk;
                pk.x = packbf(a[0] + bc, a[1] + bc);
                pk.y = packbf(a[2] + bc, a[3] + bc);
                *(u32x2*)(vrow + ((32 * jn + 8 * g) ^ sx)) = pk;
            }
        }
    }
}

// ---------------------------------------------------------------------------
// Fused attention, fully barrier-free, 32x32 tiles, in-register P.
// Wave = 64q x 64c (c-quarter w). Per 64-m chunk:
//   QK: 8x mfma_32x32x16(K,Q) -> S^T tiles; exp (raw v_exp_f32);
//   cvt_pk + v_permlane32_swap -> PV A-frags IN REGISTERS (no P LDS);
//   PV: 16x mfma_32x32x16(P, V) from wave-private double-buffered V LDS
//   (own c-quarter DMA'd by this wave; counted per-wave vmcnt only).
// LDS: 4 waves * 2 bufs * 8KB + rowsum 1KB = 66560 B -> 2 blocks/CU.
// ---------------------------------------------------------------------------
__global__ __launch_bounds__(256, 2) void attn_kernel(
    const float* __restrict__ x,
    const ushort_t* __restrict__ Qb, const ushort_t* __restrict__ Kb,
    const ushort_t* __restrict__ Vt,
    const float* __restrict__ gamma, float* __restrict__ out)
{
    __shared__ __align__(16) unsigned char smem[66560];

    const int b   = blockIdx.x & 7;
    const int n0  = (blockIdx.x >> 3) << 6;
    const int t   = threadIdx.x;
    const int l   = t & 63, w = t >> 6;
    const int l31 = l & 31, h2 = l >> 5;
    const int sxv = (l & 7) << 4;                    // matches V image swizzle
    unsigned char* wlds = smem + w * 16384;          // 2 x 8 KB private V bufs
    float* rslw = (float*)(smem + 65536) + w * 64;   // wave-private rowsums

    // Q fragments (B-role: col = l31 -> q = n0+32jq+l31; k = 16kh+8h2+j)
    short8 qfv[2][2];
    #pragma unroll
    for (int jq = 0; jq < 2; ++jq)
        #pragma unroll
        for (int kh = 0; kh < 2; ++kh)
            qfv[jq][kh] = *(const short8*)(Qb
                + (size_t)(b * N_ + n0 + 32 * jq + l31) * CQK_ + 16 * kh + 8 * h2);

    f32x16 acc[2][2];
    #pragma unroll
    for (int i = 0; i < 2; ++i)
        #pragma unroll
        for (int j = 0; j < 2; ++j)
            #pragma unroll
            for (int e = 0; e < 16; ++e) acc[i][j][e] = 0.f;
    float rs[2] = {0.f, 0.f};

    const ushort_t* Kbb = Kb + (size_t)(b * N_) * CQK_;
    const char* Vgb = (const char*)Vt + (size_t)b * 64 * 32768 + w * 8192;

    short8 kfA[2][2], kfB[2][2];

    // ---- prologue: K(0) -> kfA, DMA(0) -> buf0 (own c-quarter) ----
    #pragma unroll
    for (int jm = 0; jm < 2; ++jm)
        #pragma unroll
        for (int kh = 0; kh < 2; ++kh)
            kfA[jm][kh] = *(const short8*)(Kbb
                + (size_t)(32 * jm + l31) * CQK_ + 16 * kh + 8 * h2);
    #pragma unroll
    for (int i = 0; i < 8; ++i)
        __builtin_amdgcn_global_load_lds(
            (const __attribute__((address_space(1))) unsigned int*)(Vgb + l * 16 + i * 1024),
            (__attribute__((address_space(3))) unsigned int*)(wlds + l * 16 + i * 1024),
            16, 0, 0);

#define CHUNK_BODY(CH, KFC, KFN)                                                \
    {                                                                           \
        const int chn = ((CH) + 1) & 63;                                        \
        /* 1. K(n+1) -> regs */                                                 \
        _Pragma("unroll")                                                       \
        for (int jm = 0; jm < 2; ++jm)                                          \
            _Pragma("unroll")                                                   \
            for (int kh = 0; kh < 2; ++kh)                                      \
                KFN[jm][kh] = *(const short8*)(Kbb                              \
                    + (size_t)(64 * chn + 32 * jm + l31) * CQK_                 \
                    + 16 * kh + 8 * h2);                                        \
        /* 2. DMA(n+1) own c-quarter -> other buffer */                         \
        {                                                                       \
            const char* gsrc = Vgb + (size_t)chn * 32768 + l * 16;              \
            unsigned char* ldst = wlds + (((CH) + 1) & 1) * 8192 + l * 16;      \
            _Pragma("unroll")                                                   \
            for (int i = 0; i < 8; ++i)                                         \
                __builtin_amdgcn_global_load_lds(                               \
                    (const __attribute__((address_space(1))) unsigned int*)(gsrc + i * 1024), \
                    (__attribute__((address_space(3))) unsigned int*)(ldst + i * 1024), \
                    16, 0, 0);                                                  \
        }                                                                       \
        /* 3. QK (32x32, K=32 via 2 mfma), exp, pack, permlane -> A-frags */    \
        unsigned paw[4][2][4];                                                  \
        _Pragma("unroll")                                                       \
        for (int jm = 0; jm < 2; ++jm) {                                        \
            _Pragma("unroll")                                                   \
            for (int jq = 0; jq < 2; ++jq) {                                    \
                f32x16 sv;                                                      \
                _Pragma("unroll")                                               \
                for (int e = 0; e < 16; ++e) sv[e] = 0.f;                       \
                sv = __builtin_amdgcn_mfma_f32_32x32x16_bf16(                   \
                         KFC[jm][0], qfv[jq][0], sv, 0, 0, 0);                  \
                sv = __builtin_amdgcn_mfma_f32_32x32x16_bf16(                   \
                         KFC[jm][1], qfv[jq][1], sv, 0, 0, 0);                  \
                float ev[16];                                                   \
                _Pragma("unroll")                                               \
                for (int e = 0; e < 16; ++e) ev[e] = vexp2(sv[e]);              \
                float sm = ((ev[0] + ev[1]) + (ev[2] + ev[3]))                  \
                         + ((ev[4] + ev[5]) + (ev[6] + ev[7]))                  \
                         + ((ev[8] + ev[9]) + (ev[10] + ev[11]))                \
                         + ((ev[12] + ev[13]) + (ev[14] + ev[15]));             \
                rs[jq] += sm;                                                   \
                unsigned u0 = cvtpk(ev[0], ev[1]),   u1 = cvtpk(ev[2], ev[3]);  \
                unsigned u2 = cvtpk(ev[4], ev[5]),   u3 = cvtpk(ev[6], ev[7]);  \
                unsigned u4 = cvtpk(ev[8], ev[9]),   u5 = cvtpk(ev[10], ev[11]);\
                unsigned u6 = cvtpk(ev[12], ev[13]), u7 = cvtpk(ev[14], ev[15]);\
                plswap(u0, u2); plswap(u1, u3);                                 \
                plswap(u4, u6); plswap(u5, u7);                                 \
                paw[2 * jm + 0][jq][0] = u0; paw[2 * jm + 0][jq][1] = u1;       \
                paw[2 * jm + 0][jq][2] = u2; paw[2 * jm + 0][jq][3] = u3;       \
                paw[2 * jm + 1][jq][0] = u4; paw[2 * jm + 1][jq][1] = u5;       \
                paw[2 * jm + 1][jq][2] = u6; paw[2 * jm + 1][jq][3] = u7;       \
            }                                                                   \
        }                                                                       \
        /* 4. my DMA(n) retired; K(n+1)=4 + DMA(n+1)=8 stay in flight */        \
        asm volatile("s_waitcnt vmcnt(12)" ::: "memory");                       \
        /* 5. PV: A = register P, B = V b128 (own quarter) */                   \
        {                                                                       \
            const unsigned char* vb = wlds + ((CH) & 1) * 8192;                 \
            short8 vv[2][4];                                                    \
            _Pragma("unroll")                                                   \
            for (int jc = 0; jc < 2; ++jc)                                      \
                _Pragma("unroll")                                               \
                for (int s = 0; s < 4; ++s)                                     \
                    vv[jc][s] = *(const short8*)(vb + (32 * jc + l31) * 128     \
                                   + ((32 * s + 16 * h2) ^ sxv));               \
            _Pragma("unroll")                                                   \
            for (int jq = 0; jq < 2; ++jq)                                      \
                _Pragma("unroll")                                               \
                for (int jc = 0; jc < 2; ++jc)                                  \
                    _Pragma("unroll")                                           \
                    for (int s = 0; s < 4; ++s)                                 \
                        acc[jq][jc] = __builtin_amdgcn_mfma_f32_32x32x16_bf16(  \
                            mk8u(paw[s][jq][0], paw[s][jq][1],                  \
                                 paw[s][jq][2], paw[s][jq][3]),                 \
                            vv[jc][s], acc[jq][jc], 0, 0, 0);                   \
        }                                                                       \
    }

    for (int mc = 0; mc < 64; mc += 2) {
        CHUNK_BODY(mc,     kfA, kfB)
        CHUNK_BODY(mc + 1, kfB, kfA)
    }
#undef CHUNK_BODY

    // ---- rowsums (q = l31 per jq): halves are complementary m-sets ----
    #pragma unroll
    for (int jq = 0; jq < 2; ++jq)
        rs[jq] += __shfl_xor(rs[jq], 32, 64);
    if (l < 32) {
        rslw[l]      = rs[0];
        rslw[32 + l] = rs[1];
    }
    asm volatile("s_waitcnt lgkmcnt(0)" ::: "memory");

    // ---- epilogue: out = gamma * acc / rowsum + x ----
    const float gm = gamma[0];
    #pragma unroll
    for (int jq = 0; jq < 2; ++jq)
        #pragma unroll
        for (int rg = 0; rg < 4; ++rg) {
            f32x4 sv = *(const f32x4*)(rslw + 32 * jq + 8 * rg + 4 * h2);
            float i0 = 1.0f / sv[0], i1 = 1.0f / sv[1];
            float i2 = 1.0f / sv[2], i3 = 1.0f / sv[3];
            const int n = n0 + 32 * jq + 8 * rg + 4 * h2;
            #pragma unroll
            for (int jc = 0; jc < 2; ++jc) {
                const int c = 64 * w + 32 * jc + l31;
                const size_t rowoff = (size_t)(b * C_ + c) * N_ + n;
                float4 xv = *(const float4*)(x + rowoff);
                float4 o;
                o.x = gm * acc[jq][jc][4 * rg + 0] * i0 + xv.x;
                o.y = gm * acc[jq][jc][4 * rg + 1] * i1 + xv.y;
                o.z = gm * acc[jq][jc][4 * rg + 2] * i2 + xv.z;
                o.w = gm * acc[jq][jc][4 * rg + 3] * i3 + xv.w;
                *(float4*)(out + rowoff) = o;
            }
        }
}

// ---------------------------------------------------------------------------
extern "C" void kernel_launch(void* const* d_in, const int* in_sizes, int n_in,
                              void* d_out, int out_size, void* d_ws, size_t ws_size,
                              hipStream_t stream)
{
    const float* x     = (const float*)d_in[0];
    const float* Wq    = (const float*)d_in[1];
    const float* bq    = (const float*)d_in[2];
    const float* Wk    = (const float*)d_in[3];
    const float* bk    = (const float*)d_in[4];
    const float* Wv    = (const float*)d_in[5];
    const float* bv    = (const float*)d_in[6];
    const float* gamma = (const float*)d_in[7];
    float* out = (float*)d_out;

    ushort_t* ws = (ushort_t*)d_ws;
    ushort_t* Qb   = ws;                                  // B*N*32 bf16
    ushort_t* Kb   = Qb + (size_t)B_ * N_ * CQK_;         // B*N*32 bf16
    ushort_t* Vt   = Kb + (size_t)B_ * N_ * CQK_;         // B*64 chunks * 32KB
    ushort_t* Wall = Vt + (size_t)B_ * C_ * N_;           // 320*256 bf16
    float*    ball = (float*)(Wall + (size_t)320 * C_);   // 320 f32

    prep_kernel<<<320, 256, 0, stream>>>(Wq, bq, Wk, bk, Wv, bv, Wall, ball);
    proj_kernel<<<B_ * (N_ / 64), 256, 0, stream>>>(x, Wall, ball, Qb, Kb, Vt);
    attn_kernel<<<B_ * (N_ / 64), 256, 0, stream>>>(x, Qb, Kb, Vt, gamma, out);
}